// Round 13
// baseline (219.784 us; speedup 1.0000x reference)
//
#include <hip/hip_runtime.h>

#define DEVI __device__ __forceinline__

typedef __bf16 bf16x8 __attribute__((ext_vector_type(8)));
typedef float f32x4 __attribute__((ext_vector_type(4)));
typedef unsigned short u16x8 __attribute__((ext_vector_type(8)));

DEVI unsigned short f2bf(float f) {
  unsigned u = __builtin_bit_cast(unsigned, f);
  u += 0x7FFFu + ((u >> 16) & 1u);
  return (unsigned short)(u >> 16);
}
DEVI float bf2f(unsigned short h) {
  return __builtin_bit_cast(float, (unsigned)h << 16);
}

// ---------------- prep kernels ----------------

__global__ __launch_bounds__(256) void cast_x0_kernel(const float* __restrict__ x,
                                                      unsigned short* __restrict__ xb) {
  int i = blockIdx.x * 256 + threadIdx.x;  // i < 2097152
  const f32x4* p = (const f32x4*)x;
  f32x4 a = __builtin_nontemporal_load(p + 2 * i);
  f32x4 b = __builtin_nontemporal_load(p + 2 * i + 1);
  u16x8 o;
  o[0] = f2bf(a[0]); o[1] = f2bf(a[1]); o[2] = f2bf(a[2]); o[3] = f2bf(a[3]);
  o[4] = f2bf(b[0]); o[5] = f2bf(b[1]); o[6] = f2bf(b[2]); o[7] = f2bf(b[3]);
  __builtin_nontemporal_store(o, (u16x8*)xb + i);
}

// U[L,E,D,R] -> W1T[l][n=e*64+r][k=d] bf16
__global__ __launch_bounds__(256) void pack_w1_kernel(const float* __restrict__ U,
                                                      unsigned short* __restrict__ W1T) {
  int idx = blockIdx.x * 256 + threadIdx.x;
  int l = idx >> 18;
  int rem = idx & 262143;
  int n = rem >> 10, k = rem & 1023;
  int e = n >> 6, r = n & 63;
  W1T[idx] = f2bf(U[(size_t)(((l * 4 + e) << 10) + k) * 64 + r]);
}

// V[L,E,R,D] -> V2T[l][d][c=e*64+r] bf16
__global__ __launch_bounds__(256) void pack_v2_kernel(const float* __restrict__ V,
                                                      unsigned short* __restrict__ V2T) {
  int idx = blockIdx.x * 256 + threadIdx.x;
  int l = idx >> 18;
  int rem = idx & 262143;
  int d = rem >> 8, c = rem & 255;
  int e = c >> 6, r = c & 63;
  V2T[idx] = f2bf(V[(size_t)(((l * 4 + e) * 64 + r) << 10) + d]);
}

// gW[L,1024,4] fp32 -> gWT[l][n=0..15][k] bf16 (n>=4 zero-padded)
__global__ __launch_bounds__(256) void pack_gw_kernel(const float* __restrict__ gW,
                                                      unsigned short* __restrict__ gWT) {
  int idx = blockIdx.x * 256 + threadIdx.x;  // < 49152
  int l = idx >> 14;
  int n = (idx >> 10) & 15;
  int k = idx & 1023;
  float v = (n < 4) ? gW[l * 4096 + k * 4 + n] : 0.0f;
  gWT[idx] = f2bf(v);
}

// ---------------- GEMM1 + fused gate: hg = relu(x@W1) * softmax(x@gW+gb) ----------------
// BM=32 BN=128 BK=64, 4 waves 2x2, wave tile 16x64. 1024 blocks, XCD-paired remap.
__global__ __launch_bounds__(256) void k1_kernel(const unsigned short* __restrict__ A,
                                                 const unsigned short* __restrict__ Bw,
                                                 const unsigned short* __restrict__ gWT,
                                                 const float* __restrict__ gb,
                                                 unsigned short* __restrict__ Hg) {
  constexpr int K = 1024;
  __shared__ char lds[20480];  // As 4KB | Bs 16KB (reused: hg bounce 8KB)
  __shared__ float gls[128];   // gate [32][4]
  int t = threadIdx.x;
  int wid = t >> 6, lane = t & 63;
  int g4 = lane >> 4, l15 = lane & 15;
  int wm = wid >> 1, wn = wid & 1;

  // XCD-pair remap: j -> (p in [0,512), ybl in {0,1})
  int j = blockIdx.x;
  int s = j >> 3;
  int p = (j & 7) * 64 + (s >> 1);
  int ybl = s & 1;
  int m0 = p * 32, n0 = ybl * 128;

  int srow = t >> 3;
  int scolb = ((t & 7) * 16) ^ ((srow & 7) << 4);
  const unsigned short* Asrc = A + (size_t)(m0 + srow) * K + (scolb >> 1);
  const unsigned short* Bsrc = Bw + (size_t)(n0 + srow) * K + (scolb >> 1);

  f32x4 acc[4], accg;
  {
    f32x4 z = {0.f, 0.f, 0.f, 0.f};
    accg = z;
#pragma unroll
    for (int n = 0; n < 4; ++n) acc[n] = z;
  }

  for (int ks = 0; ks < K; ks += 64) {
    __syncthreads();
    __builtin_amdgcn_global_load_lds(
        (const __attribute__((address_space(1))) void*)(Asrc + ks),
        (__attribute__((address_space(3))) void*)(lds + wid * 1024), 16, 0, 0);
#pragma unroll
    for (int i = 0; i < 4; ++i)
      __builtin_amdgcn_global_load_lds(
          (const __attribute__((address_space(1))) void*)(Bsrc + (size_t)i * 32 * K + ks),
          (__attribute__((address_space(3))) void*)(lds + 4096 + i * 4096 + wid * 1024), 16, 0, 0);
    __syncthreads();
#pragma unroll
    for (int kk = 0; kk < 2; ++kk) {
      bf16x8 af;
      {
        int row = wm * 16 + l15;
        af = *(const bf16x8*)(lds + row * 128 + ((kk * 64 + g4 * 16) ^ ((row & 7) << 4)));
      }
      bf16x8 gf;
      if (wn == 0) gf = *(const bf16x8*)(gWT + (size_t)l15 * 1024 + ks + kk * 32 + g4 * 8);
#pragma unroll
      for (int n = 0; n < 4; ++n) {
        int row = wn * 64 + n * 16 + l15;
        bf16x8 bfr = *(const bf16x8*)(lds + 4096 + row * 128 +
                                      ((kk * 64 + g4 * 16) ^ ((row & 7) << 4)));
        acc[n] = __builtin_amdgcn_mfma_f32_16x16x32_bf16(af, bfr, acc[n], 0, 0, 0);
      }
      if (wn == 0)
        accg = __builtin_amdgcn_mfma_f32_16x16x32_bf16(af, gf, accg, 0, 0, 0);
    }
  }

  // gate softmax: wn==0 waves
  if (wn == 0) {
    float gbv = gb[l15 & 3];
#pragma unroll
    for (int jj = 0; jj < 4; ++jj) {
      float v = accg[jj] + gbv;
      float mx = fmaxf(v, __shfl_xor(v, 1));
      mx = fmaxf(mx, __shfl_xor(mx, 2));
      float ev = __expf(v - mx);
      float sm = ev + __shfl_xor(ev, 1);
      sm += __shfl_xor(sm, 2);
      if (l15 < 4) gls[(wm * 16 + g4 * 4 + jj) * 4 + l15] = ev / sm;
    }
  }
  __syncthreads();

  // bounce: relu*gate -> bf16 into Bs region
  int e = ybl * 2 + wn;
#pragma unroll
  for (int n = 0; n < 4; ++n) {
#pragma unroll
    for (int jj = 0; jj < 4; ++jj) {
      int row = wm * 16 + g4 * 4 + jj;
      int col = wn * 64 + n * 16 + l15;
      float v = fmaxf(acc[n][jj], 0.f) * gls[row * 4 + e];
      *(unsigned short*)(lds + 4096 + row * 256 + ((col * 2) ^ ((row & 7) << 4))) = f2bf(v);
    }
  }
  __syncthreads();

#pragma unroll
  for (int i = 0; i < 2; ++i) {
    int row = i * 16 + (t >> 4);
    int seg = (t & 15) * 16;
    u16x8 v = *(const u16x8*)(lds + 4096 + row * 256 + (seg ^ ((row & 7) << 4)));
    *(u16x8*)(Hg + (size_t)(m0 + row) * 256 + n0 + (seg >> 1)) = v;
  }
}

// ---------------- GEMM2 + residual epilogue (bounced, coalesced, nt-stream) ----------------
// BM=64 BN=128 BK=64. 2048 blocks, XCD-paired remap.
__global__ __launch_bounds__(256) void k2_kernel(const unsigned short* __restrict__ A,
                                                 const unsigned short* __restrict__ Bw,
                                                 const unsigned short* __restrict__ x0b,
                                                 const float* __restrict__ x0f,
                                                 const unsigned short* __restrict__ xcur,
                                                 const float* __restrict__ biasl,
                                                 unsigned short* __restrict__ xnext,
                                                 float* __restrict__ out,
                                                 int last, int use_x0b) {
  constexpr int K = 256;
  __shared__ char lds[24576];  // As 8KB | Bs 16KB (Bs reused as acc bounce)
  int t = threadIdx.x;
  int wid = t >> 6, lane = t & 63;
  int g4 = lane >> 4, l15 = lane & 15;
  int wm = wid >> 1, wn = wid & 1;

  // XCD-pair remap: j in [0,2048) -> (xbl in [0,256), ybl in [0,8))
  int j = blockIdx.x;
  int s = j >> 3;
  int xbl = (j & 7) * 32 + (s >> 3);
  int ybl = s & 7;
  int m0 = xbl * 64, n0 = ybl * 128;

  int srow = t >> 3;
  int scolb = ((t & 7) * 16) ^ ((srow & 7) << 4);
  const unsigned short* Asrc = A + (size_t)(m0 + srow) * K + (scolb >> 1);
  const unsigned short* Bsrc = Bw + (size_t)(n0 + srow) * K + (scolb >> 1);

  f32x4 acc[2][4];
#pragma unroll
  for (int m = 0; m < 2; ++m)
#pragma unroll
    for (int n = 0; n < 4; ++n) { f32x4 z = {0.f, 0.f, 0.f, 0.f}; acc[m][n] = z; }

  for (int ks = 0; ks < K; ks += 64) {
    __syncthreads();
#pragma unroll
    for (int i = 0; i < 2; ++i)
      __builtin_amdgcn_global_load_lds(
          (const __attribute__((address_space(1))) void*)(Asrc + (size_t)i * 32 * K + ks),
          (__attribute__((address_space(3))) void*)(lds + i * 4096 + wid * 1024), 16, 0, 0);
#pragma unroll
    for (int i = 0; i < 4; ++i)
      __builtin_amdgcn_global_load_lds(
          (const __attribute__((address_space(1))) void*)(Bsrc + (size_t)i * 32 * K + ks),
          (__attribute__((address_space(3))) void*)(lds + 8192 + i * 4096 + wid * 1024), 16, 0, 0);
    __syncthreads();
#pragma unroll
    for (int kk = 0; kk < 2; ++kk) {
      bf16x8 af[2];
#pragma unroll
      for (int m = 0; m < 2; ++m) {
        int row = wm * 32 + m * 16 + l15;
        af[m] = *(const bf16x8*)(lds + row * 128 + ((kk * 64 + g4 * 16) ^ ((row & 7) << 4)));
      }
#pragma unroll
      for (int n = 0; n < 4; ++n) {
        int row = wn * 64 + n * 16 + l15;
        bf16x8 bfr = *(const bf16x8*)(lds + 8192 + row * 128 +
                                      ((kk * 64 + g4 * 16) ^ ((row & 7) << 4)));
#pragma unroll
        for (int m = 0; m < 2; ++m)
          acc[m][n] = __builtin_amdgcn_mfma_f32_16x16x32_bf16(af[m], bfr, acc[m][n], 0, 0, 0);
      }
    }
  }
  __syncthreads();

  // bounce mixed (acc) as bf16 into Bs region
#pragma unroll
  for (int m = 0; m < 2; ++m) {
#pragma unroll
    for (int n = 0; n < 4; ++n) {
#pragma unroll
      for (int jj = 0; jj < 4; ++jj) {
        int row = wm * 32 + m * 16 + g4 * 4 + jj;
        int col = wn * 64 + n * 16 + l15;
        *(unsigned short*)(lds + 8192 + row * 256 + ((col * 2) ^ ((row & 7) << 4))) =
            f2bf(acc[m][n][jj]);
      }
    }
  }
  __syncthreads();

  // store pass: coalesced epilogue; stream traffic (xcur/x0b/out/xnext) is non-temporal
#pragma unroll
  for (int i = 0; i < 4; ++i) {
    int row = i * 16 + (t >> 4);
    int seg = (t & 15) * 16;
    u16x8 a8 = *(const u16x8*)(lds + 8192 + row * 256 + (seg ^ ((row & 7) << 4)));
    size_t goff = (size_t)(m0 + row) * 1024 + n0 + (seg >> 1);
    u16x8 cv = __builtin_nontemporal_load((const u16x8*)(xcur + goff));
    float x0v[8];
    if (use_x0b) {
      u16x8 xv = __builtin_nontemporal_load((const u16x8*)(x0b + goff));
#pragma unroll
      for (int k = 0; k < 8; ++k) x0v[k] = bf2f(xv[k]);
    } else {
      f32x4 xa = *(const f32x4*)(x0f + goff);
      f32x4 xb2 = *(const f32x4*)(x0f + goff + 4);
#pragma unroll
      for (int k = 0; k < 4; ++k) { x0v[k] = xa[k]; x0v[k + 4] = xb2[k]; }
    }
    const float* bp = biasl + n0 + (seg >> 1);
    f32x4 b0 = *(const f32x4*)bp;
    f32x4 b1 = *(const f32x4*)(bp + 4);
    float r[8];
#pragma unroll
    for (int k = 0; k < 8; ++k) {
      float bv = (k < 4) ? b0[k & 3] : b1[k & 3];
      r[k] = x0v[k] * bf2f(a8[k]) + bv + bf2f(cv[k]);
    }
    if (last) {
      f32x4 r0, r1;
#pragma unroll
      for (int k = 0; k < 4; ++k) { r0[k] = r[k]; r1[k] = r[k + 4]; }
      __builtin_nontemporal_store(r0, (f32x4*)(out + goff));
      __builtin_nontemporal_store(r1, (f32x4*)(out + goff + 4));
    } else {
      u16x8 o;
#pragma unroll
      for (int k = 0; k < 8; ++k) o[k] = f2bf(r[k]);
      __builtin_nontemporal_store(o, (u16x8*)(xnext + goff));
    }
  }
}

// ---------------- host ----------------
extern "C" void kernel_launch(void* const* d_in, const int* in_sizes, int n_in,
                              void* d_out, int out_size, void* d_ws, size_t ws_size,
                              hipStream_t stream) {
  const float* x0 = (const float*)d_in[0];
  const float* U = (const float*)d_in[1];
  const float* V = (const float*)d_in[2];
  const float* gW = (const float*)d_in[3];
  const float* gb = (const float*)d_in[4];
  const float* bias = (const float*)d_in[5];
  float* out = (float*)d_out;
  char* ws = (char*)d_ws;

  const size_t SZ_X = 33554432;   // 16384*1024*2
  const size_t SZ_HG = 8388608;   // 16384*256*2
  const size_t SZ_W = 1572864;    // 3*256*1024*2
  const size_t SZ_GW = 98304;     // 3*16*1024*2
  bool use_x0b = ws_size >= (2 * SZ_X + SZ_HG + 2 * SZ_W + SZ_GW);

  size_t off = 0;
  unsigned short* x0b = nullptr;
  if (use_x0b) { x0b = (unsigned short*)(ws + off); off += SZ_X; }
  unsigned short* xbf = (unsigned short*)(ws + off); off += SZ_X;
  unsigned short* hg = (unsigned short*)(ws + off); off += SZ_HG;
  unsigned short* W1T = (unsigned short*)(ws + off); off += SZ_W;
  unsigned short* V2T = (unsigned short*)(ws + off); off += SZ_W;
  unsigned short* gWT = (unsigned short*)(ws + off); off += SZ_GW;

  unsigned short* xinit = use_x0b ? x0b : xbf;  // bf16 copy of x0

  cast_x0_kernel<<<8192, 256, 0, stream>>>(x0, xinit);
  pack_w1_kernel<<<3072, 256, 0, stream>>>(U, W1T);
  pack_v2_kernel<<<3072, 256, 0, stream>>>(V, V2T);
  pack_gw_kernel<<<192, 256, 0, stream>>>(gW, gWT);

  for (int l = 0; l < 3; ++l) {
    const unsigned short* xs = (l == 0) ? xinit : xbf;
    k1_kernel<<<1024, 256, 0, stream>>>(xs, W1T + l * 262144, gWT + l * 16384,
                                        gb + l * 4, hg);
    k2_kernel<<<2048, 256, 0, stream>>>(hg, V2T + l * 262144,
                                        use_x0b ? x0b : nullptr, x0, xs,
                                        bias + l * 1024, xbf, out,
                                        (l == 2) ? 1 : 0, use_x0b ? 1 : 0);
  }
}

// Round 14
// 198.354 us; speedup vs baseline: 1.1080x; 1.1080x over previous
//
#include <hip/hip_runtime.h>

#define DEVI __device__ __forceinline__

typedef __bf16 bf16x8 __attribute__((ext_vector_type(8)));
typedef float f32x4 __attribute__((ext_vector_type(4)));
typedef unsigned short u16x8 __attribute__((ext_vector_type(8)));

DEVI unsigned short f2bf(float f) {
  unsigned u = __builtin_bit_cast(unsigned, f);
  u += 0x7FFFu + ((u >> 16) & 1u);
  return (unsigned short)(u >> 16);
}
DEVI float bf2f(unsigned short h) {
  return __builtin_bit_cast(float, (unsigned)h << 16);
}

// ---------------- prep kernels ----------------

__global__ __launch_bounds__(256) void cast_x0_kernel(const float* __restrict__ x,
                                                      unsigned short* __restrict__ xb) {
  int i = blockIdx.x * 256 + threadIdx.x;  // i < 2097152
  const f32x4* p = (const f32x4*)x;
  f32x4 a = p[2 * i], b = p[2 * i + 1];
  u16x8 o;
  o[0] = f2bf(a[0]); o[1] = f2bf(a[1]); o[2] = f2bf(a[2]); o[3] = f2bf(a[3]);
  o[4] = f2bf(b[0]); o[5] = f2bf(b[1]); o[6] = f2bf(b[2]); o[7] = f2bf(b[3]);
  ((u16x8*)xb)[i] = o;
}

// U[L,E,D,R] -> W1T[l][n=e*64+r][k=d] bf16
__global__ __launch_bounds__(256) void pack_w1_kernel(const float* __restrict__ U,
                                                      unsigned short* __restrict__ W1T) {
  int idx = blockIdx.x * 256 + threadIdx.x;
  int l = idx >> 18;
  int rem = idx & 262143;
  int n = rem >> 10, k = rem & 1023;
  int e = n >> 6, r = n & 63;
  W1T[idx] = f2bf(U[(size_t)(((l * 4 + e) << 10) + k) * 64 + r]);
}

// V[L,E,R,D] -> V2T[l][d][c=e*64+r] bf16
__global__ __launch_bounds__(256) void pack_v2_kernel(const float* __restrict__ V,
                                                      unsigned short* __restrict__ V2T) {
  int idx = blockIdx.x * 256 + threadIdx.x;
  int l = idx >> 18;
  int rem = idx & 262143;
  int d = rem >> 8, c = rem & 255;
  int e = c >> 6, r = c & 63;
  V2T[idx] = f2bf(V[(size_t)(((l * 4 + e) * 64 + r) << 10) + d]);
}

// gW[L,1024,4] fp32 -> gWT[l][n=0..15][k] bf16 (n>=4 zero-padded)
__global__ __launch_bounds__(256) void pack_gw_kernel(const float* __restrict__ gW,
                                                      unsigned short* __restrict__ gWT) {
  int idx = blockIdx.x * 256 + threadIdx.x;  // < 49152
  int l = idx >> 14;
  int n = (idx >> 10) & 15;
  int k = idx & 1023;
  float v = (n < 4) ? gW[l * 4096 + k * 4 + n] : 0.0f;
  gWT[idx] = f2bf(v);
}

// ---------------- GEMM1 + fused gate: hg = relu(x@W1) * softmax(x@gW+gb) ----------------
// BM=32 BN=64 BK=64, 4 waves 2x2, wave tile 16x32. LDS 12KB -> 8 blocks/CU (full occ).
// grid 2048; XCD-quad remap: 4 siblings sharing an A-tile -> same XCD, adjacent.
__global__ __launch_bounds__(256) void k1_kernel(const unsigned short* __restrict__ A,
                                                 const unsigned short* __restrict__ Bw,
                                                 const unsigned short* __restrict__ gWT,
                                                 const float* __restrict__ gb,
                                                 unsigned short* __restrict__ Hg) {
  constexpr int K = 1024;
  __shared__ char lds[12288];  // As 4KB [0,4096) | Bs 8KB [4096,12288); bounce reuses Bs
  __shared__ float gls[128];   // gate [32][4]
  int t = threadIdx.x;
  int wid = t >> 6, lane = t & 63;
  int g4 = lane >> 4, l15 = lane & 15;
  int wm = wid >> 1, wn = wid & 1;

  // remap: j in [0,2048) -> (p in [0,512), ybl in [0,4)); siblings j,j+8,j+16,j+24
  int j = blockIdx.x;
  int s = j >> 3;
  int p = (j & 7) * 64 + (s >> 2);
  int ybl = s & 3;
  int m0 = p * 32, n0 = ybl * 64;

  int srow = t >> 3;
  int scolb = ((t & 7) * 16) ^ ((srow & 7) << 4);
  const unsigned short* Asrc = A + (size_t)(m0 + srow) * K + (scolb >> 1);
  const unsigned short* Bsrc = Bw + (size_t)(n0 + srow) * K + (scolb >> 1);

  f32x4 acc[2], accg;
  {
    f32x4 z = {0.f, 0.f, 0.f, 0.f};
    accg = z;
    acc[0] = z; acc[1] = z;
  }

  for (int ks = 0; ks < K; ks += 64) {
    __syncthreads();
    __builtin_amdgcn_global_load_lds(
        (const __attribute__((address_space(1))) void*)(Asrc + ks),
        (__attribute__((address_space(3))) void*)(lds + wid * 1024), 16, 0, 0);
#pragma unroll
    for (int i = 0; i < 2; ++i)
      __builtin_amdgcn_global_load_lds(
          (const __attribute__((address_space(1))) void*)(Bsrc + (size_t)i * 32 * K + ks),
          (__attribute__((address_space(3))) void*)(lds + 4096 + i * 4096 + wid * 1024), 16, 0, 0);
    __syncthreads();
#pragma unroll
    for (int kk = 0; kk < 2; ++kk) {
      bf16x8 af;
      {
        int row = wm * 16 + l15;
        af = *(const bf16x8*)(lds + row * 128 + ((kk * 64 + g4 * 16) ^ ((row & 7) << 4)));
      }
      bf16x8 gf;
      if (wn == 0) gf = *(const bf16x8*)(gWT + (size_t)l15 * 1024 + ks + kk * 32 + g4 * 8);
#pragma unroll
      for (int n = 0; n < 2; ++n) {
        int row = wn * 32 + n * 16 + l15;
        bf16x8 bfr = *(const bf16x8*)(lds + 4096 + row * 128 +
                                      ((kk * 64 + g4 * 16) ^ ((row & 7) << 4)));
        acc[n] = __builtin_amdgcn_mfma_f32_16x16x32_bf16(af, bfr, acc[n], 0, 0, 0);
      }
      if (wn == 0)
        accg = __builtin_amdgcn_mfma_f32_16x16x32_bf16(af, gf, accg, 0, 0, 0);
    }
  }

  // gate softmax: wn==0 waves (wm 0: rows 0-15, wm 1: rows 16-31)
  if (wn == 0) {
    float gbv = gb[l15 & 3];
#pragma unroll
    for (int jj = 0; jj < 4; ++jj) {
      float v = accg[jj] + gbv;
      float mx = fmaxf(v, __shfl_xor(v, 1));
      mx = fmaxf(mx, __shfl_xor(mx, 2));
      float ev = __expf(v - mx);
      float sm = ev + __shfl_xor(ev, 1);
      sm += __shfl_xor(sm, 2);
      if (l15 < 4) gls[(wm * 16 + g4 * 4 + jj) * 4 + l15] = ev / sm;
    }
  }
  __syncthreads();

  // bounce: relu*gate -> bf16 into Bs region ([32] rows x 128B, swizzled); expert e = ybl
#pragma unroll
  for (int n = 0; n < 2; ++n) {
#pragma unroll
    for (int jj = 0; jj < 4; ++jj) {
      int row = wm * 16 + g4 * 4 + jj;
      int col = wn * 32 + n * 16 + l15;
      float v = fmaxf(acc[n][jj], 0.f) * gls[row * 4 + ybl];
      *(unsigned short*)(lds + 4096 + row * 128 + ((col * 2) ^ ((row & 7) << 4))) = f2bf(v);
    }
  }
  __syncthreads();

  // coalesced store: single pass, 8 lanes cover one 128B row span
  {
    int row = t >> 3;
    int seg = (t & 7) * 16;
    u16x8 v = *(const u16x8*)(lds + 4096 + row * 128 + (seg ^ ((row & 7) << 4)));
    *(u16x8*)(Hg + (size_t)(m0 + row) * 256 + n0 + (seg >> 1)) = v;
  }
}

// ---------------- GEMM2 + residual epilogue ----------------
// BM=32 BN=64 BK=64, 4 waves 2x2, wave tile 16x32. LDS 12KB -> 8 blocks/CU.
// grid 8192; XCD-16 remap: 16 siblings sharing an hg band -> same XCD, adjacent.
__global__ __launch_bounds__(256) void k2_kernel(const unsigned short* __restrict__ A,
                                                 const unsigned short* __restrict__ Bw,
                                                 const unsigned short* __restrict__ x0b,
                                                 const float* __restrict__ x0f,
                                                 const unsigned short* __restrict__ xcur,
                                                 const float* __restrict__ biasl,
                                                 unsigned short* __restrict__ xnext,
                                                 float* __restrict__ out,
                                                 int last, int use_x0b) {
  constexpr int K = 256;
  __shared__ char lds[12288];  // As 4KB [0,4096) | Bs 8KB [4096,12288); bounce reuses Bs
  int t = threadIdx.x;
  int wid = t >> 6, lane = t & 63;
  int g4 = lane >> 4, l15 = lane & 15;
  int wm = wid >> 1, wn = wid & 1;

  // remap: j in [0,8192) -> (xbl in [0,512), ybl in [0,16)); siblings j,j+8,...,j+120
  int j = blockIdx.x;
  int s = j >> 3;
  int xbl = (j & 7) * 64 + (s >> 4);
  int ybl = s & 15;
  int m0 = xbl * 32, n0 = ybl * 64;

  int srow = t >> 3;
  int scolb = ((t & 7) * 16) ^ ((srow & 7) << 4);
  const unsigned short* Asrc = A + (size_t)(m0 + srow) * K + (scolb >> 1);
  const unsigned short* Bsrc = Bw + (size_t)(n0 + srow) * K + (scolb >> 1);

  f32x4 acc[2];
  { f32x4 z = {0.f, 0.f, 0.f, 0.f}; acc[0] = z; acc[1] = z; }

  for (int ks = 0; ks < K; ks += 64) {
    __syncthreads();
    __builtin_amdgcn_global_load_lds(
        (const __attribute__((address_space(1))) void*)(Asrc + ks),
        (__attribute__((address_space(3))) void*)(lds + wid * 1024), 16, 0, 0);
#pragma unroll
    for (int i = 0; i < 2; ++i)
      __builtin_amdgcn_global_load_lds(
          (const __attribute__((address_space(1))) void*)(Bsrc + (size_t)i * 32 * K + ks),
          (__attribute__((address_space(3))) void*)(lds + 4096 + i * 4096 + wid * 1024), 16, 0, 0);
    __syncthreads();
#pragma unroll
    for (int kk = 0; kk < 2; ++kk) {
      bf16x8 af;
      {
        int row = wm * 16 + l15;
        af = *(const bf16x8*)(lds + row * 128 + ((kk * 64 + g4 * 16) ^ ((row & 7) << 4)));
      }
#pragma unroll
      for (int n = 0; n < 2; ++n) {
        int row = wn * 32 + n * 16 + l15;
        bf16x8 bfr = *(const bf16x8*)(lds + 4096 + row * 128 +
                                      ((kk * 64 + g4 * 16) ^ ((row & 7) << 4)));
        acc[n] = __builtin_amdgcn_mfma_f32_16x16x32_bf16(af, bfr, acc[n], 0, 0, 0);
      }
    }
  }
  __syncthreads();

  // bounce mixed (acc) as bf16 into Bs region ([32] rows x 128B, swizzled)
#pragma unroll
  for (int n = 0; n < 2; ++n) {
#pragma unroll
    for (int jj = 0; jj < 4; ++jj) {
      int row = wm * 16 + g4 * 4 + jj;
      int col = wn * 32 + n * 16 + l15;
      *(unsigned short*)(lds + 4096 + row * 128 + ((col * 2) ^ ((row & 7) << 4))) =
          f2bf(acc[n][jj]);
    }
  }
  __syncthreads();

  // store pass: single fully-coalesced pass (8 lanes per 128B row span)
  {
    int row = t >> 3;
    int seg = (t & 7) * 16;
    u16x8 a8 = *(const u16x8*)(lds + 4096 + row * 128 + (seg ^ ((row & 7) << 4)));
    size_t goff = (size_t)(m0 + row) * 1024 + n0 + (seg >> 1);
    u16x8 cv = *(const u16x8*)(xcur + goff);
    float x0v[8];
    if (use_x0b) {
      u16x8 xv = *(const u16x8*)(x0b + goff);
#pragma unroll
      for (int k = 0; k < 8; ++k) x0v[k] = bf2f(xv[k]);
    } else {
      f32x4 xa = *(const f32x4*)(x0f + goff);
      f32x4 xb2 = *(const f32x4*)(x0f + goff + 4);
#pragma unroll
      for (int k = 0; k < 4; ++k) { x0v[k] = xa[k]; x0v[k + 4] = xb2[k]; }
    }
    const float* bp = biasl + n0 + (seg >> 1);
    f32x4 b0 = *(const f32x4*)bp;
    f32x4 b1 = *(const f32x4*)(bp + 4);
    float r[8];
#pragma unroll
    for (int k = 0; k < 8; ++k) {
      float bv = (k < 4) ? b0[k & 3] : b1[k & 3];
      r[k] = x0v[k] * bf2f(a8[k]) + bv + bf2f(cv[k]);
    }
    if (last) {
      f32x4 r0, r1;
#pragma unroll
      for (int k = 0; k < 4; ++k) { r0[k] = r[k]; r1[k] = r[k + 4]; }
      *(f32x4*)(out + goff) = r0;
      *(f32x4*)(out + goff + 4) = r1;
    } else {
      u16x8 o;
#pragma unroll
      for (int k = 0; k < 8; ++k) o[k] = f2bf(r[k]);
      *(u16x8*)(xnext + goff) = o;
    }
  }
}

// ---------------- host ----------------
extern "C" void kernel_launch(void* const* d_in, const int* in_sizes, int n_in,
                              void* d_out, int out_size, void* d_ws, size_t ws_size,
                              hipStream_t stream) {
  const float* x0 = (const float*)d_in[0];
  const float* U = (const float*)d_in[1];
  const float* V = (const float*)d_in[2];
  const float* gW = (const float*)d_in[3];
  const float* gb = (const float*)d_in[4];
  const float* bias = (const float*)d_in[5];
  float* out = (float*)d_out;
  char* ws = (char*)d_ws;

  const size_t SZ_X = 33554432;   // 16384*1024*2
  const size_t SZ_HG = 8388608;   // 16384*256*2
  const size_t SZ_W = 1572864;    // 3*256*1024*2
  const size_t SZ_GW = 98304;     // 3*16*1024*2
  bool use_x0b = ws_size >= (2 * SZ_X + SZ_HG + 2 * SZ_W + SZ_GW);

  size_t off = 0;
  unsigned short* x0b = nullptr;
  if (use_x0b) { x0b = (unsigned short*)(ws + off); off += SZ_X; }
  unsigned short* xbf = (unsigned short*)(ws + off); off += SZ_X;
  unsigned short* hg = (unsigned short*)(ws + off); off += SZ_HG;
  unsigned short* W1T = (unsigned short*)(ws + off); off += SZ_W;
  unsigned short* V2T = (unsigned short*)(ws + off); off += SZ_W;
  unsigned short* gWT = (unsigned short*)(ws + off); off += SZ_GW;

  unsigned short* xinit = use_x0b ? x0b : xbf;  // bf16 copy of x0

  cast_x0_kernel<<<8192, 256, 0, stream>>>(x0, xinit);
  pack_w1_kernel<<<3072, 256, 0, stream>>>(U, W1T);
  pack_v2_kernel<<<3072, 256, 0, stream>>>(V, V2T);
  pack_gw_kernel<<<192, 256, 0, stream>>>(gW, gWT);

  for (int l = 0; l < 3; ++l) {
    const unsigned short* xs = (l == 0) ? xinit : xbf;
    k1_kernel<<<2048, 256, 0, stream>>>(xs, W1T + l * 262144, gWT + l * 16384,
                                        gb + l * 4, hg);
    k2_kernel<<<8192, 256, 0, stream>>>(hg, V2T + l * 262144,
                                        use_x0b ? x0b : nullptr, x0, xs,
                                        bias + l * 1024, xbf, out,
                                        (l == 2) ? 1 : 0, use_x0b ? 1 : 0);
  }
}

// Round 15
// 175.641 us; speedup vs baseline: 1.2513x; 1.1293x over previous
//
#include <hip/hip_runtime.h>

#define DEVI __device__ __forceinline__

typedef __bf16 bf16x8 __attribute__((ext_vector_type(8)));
typedef float f32x4 __attribute__((ext_vector_type(4)));
typedef unsigned short u16x8 __attribute__((ext_vector_type(8)));

DEVI unsigned short f2bf(float f) {
  unsigned u = __builtin_bit_cast(unsigned, f);
  u += 0x7FFFu + ((u >> 16) & 1u);
  return (unsigned short)(u >> 16);
}
DEVI float bf2f(unsigned short h) {
  return __builtin_bit_cast(float, (unsigned)h << 16);
}

// ---------------- prep kernels ----------------

__global__ __launch_bounds__(256) void cast_x0_kernel(const float* __restrict__ x,
                                                      unsigned short* __restrict__ xb) {
  int i = blockIdx.x * 256 + threadIdx.x;  // i < 2097152
  const f32x4* p = (const f32x4*)x;
  f32x4 a = p[2 * i], b = p[2 * i + 1];
  u16x8 o;
  o[0] = f2bf(a[0]); o[1] = f2bf(a[1]); o[2] = f2bf(a[2]); o[3] = f2bf(a[3]);
  o[4] = f2bf(b[0]); o[5] = f2bf(b[1]); o[6] = f2bf(b[2]); o[7] = f2bf(b[3]);
  ((u16x8*)xb)[i] = o;
}

// U[L,E,D,R] -> W1T[l][n=e*64+r][k=d] bf16
__global__ __launch_bounds__(256) void pack_w1_kernel(const float* __restrict__ U,
                                                      unsigned short* __restrict__ W1T) {
  int idx = blockIdx.x * 256 + threadIdx.x;
  int l = idx >> 18;
  int rem = idx & 262143;
  int n = rem >> 10, k = rem & 1023;
  int e = n >> 6, r = n & 63;
  W1T[idx] = f2bf(U[(size_t)(((l * 4 + e) << 10) + k) * 64 + r]);
}

// V[L,E,R,D] -> V2T[l][d][c=e*64+r] bf16
__global__ __launch_bounds__(256) void pack_v2_kernel(const float* __restrict__ V,
                                                      unsigned short* __restrict__ V2T) {
  int idx = blockIdx.x * 256 + threadIdx.x;
  int l = idx >> 18;
  int rem = idx & 262143;
  int d = rem >> 8, c = rem & 255;
  int e = c >> 6, r = c & 63;
  V2T[idx] = f2bf(V[(size_t)(((l * 4 + e) * 64 + r) << 10) + d]);
}

// gW[L,1024,4] fp32 -> gWT[l][n=0..15][k] bf16 (n>=4 zero-padded)
__global__ __launch_bounds__(256) void pack_gw_kernel(const float* __restrict__ gW,
                                                      unsigned short* __restrict__ gWT) {
  int idx = blockIdx.x * 256 + threadIdx.x;  // < 49152
  int l = idx >> 14;
  int n = (idx >> 10) & 15;
  int k = idx & 1023;
  float v = (n < 4) ? gW[l * 4096 + k * 4 + n] : 0.0f;
  gWT[idx] = f2bf(v);
}

// ---------------- GEMM1 + fused gate: hg = relu(x@W1) * softmax(x@gW+gb) ----------------
// BM=32 BN=128 BK=64, 4 waves 2x2, wave tile 16x64. 1024 blocks, XCD-paired remap.
__global__ __launch_bounds__(256) void k1_kernel(const unsigned short* __restrict__ A,
                                                 const unsigned short* __restrict__ Bw,
                                                 const unsigned short* __restrict__ gWT,
                                                 const float* __restrict__ gb,
                                                 unsigned short* __restrict__ Hg) {
  constexpr int K = 1024;
  __shared__ char lds[20480];  // As 4KB | Bs 16KB (reused: hg bounce 8KB)
  __shared__ float gls[128];   // gate [32][4]
  int t = threadIdx.x;
  int wid = t >> 6, lane = t & 63;
  int g4 = lane >> 4, l15 = lane & 15;
  int wm = wid >> 1, wn = wid & 1;

  // XCD-pair remap: j -> (p in [0,512), ybl in {0,1})
  int j = blockIdx.x;
  int s = j >> 3;
  int p = (j & 7) * 64 + (s >> 1);
  int ybl = s & 1;
  int m0 = p * 32, n0 = ybl * 128;

  int srow = t >> 3;
  int scolb = ((t & 7) * 16) ^ ((srow & 7) << 4);
  const unsigned short* Asrc = A + (size_t)(m0 + srow) * K + (scolb >> 1);
  const unsigned short* Bsrc = Bw + (size_t)(n0 + srow) * K + (scolb >> 1);

  f32x4 acc[4], accg;
  {
    f32x4 z = {0.f, 0.f, 0.f, 0.f};
    accg = z;
#pragma unroll
    for (int n = 0; n < 4; ++n) acc[n] = z;
  }

  for (int ks = 0; ks < K; ks += 64) {
    __syncthreads();
    __builtin_amdgcn_global_load_lds(
        (const __attribute__((address_space(1))) void*)(Asrc + ks),
        (__attribute__((address_space(3))) void*)(lds + wid * 1024), 16, 0, 0);
#pragma unroll
    for (int i = 0; i < 4; ++i)
      __builtin_amdgcn_global_load_lds(
          (const __attribute__((address_space(1))) void*)(Bsrc + (size_t)i * 32 * K + ks),
          (__attribute__((address_space(3))) void*)(lds + 4096 + i * 4096 + wid * 1024), 16, 0, 0);
    __syncthreads();
#pragma unroll
    for (int kk = 0; kk < 2; ++kk) {
      bf16x8 af;
      {
        int row = wm * 16 + l15;
        af = *(const bf16x8*)(lds + row * 128 + ((kk * 64 + g4 * 16) ^ ((row & 7) << 4)));
      }
      bf16x8 gf;
      if (wn == 0) gf = *(const bf16x8*)(gWT + (size_t)l15 * 1024 + ks + kk * 32 + g4 * 8);
#pragma unroll
      for (int n = 0; n < 4; ++n) {
        int row = wn * 64 + n * 16 + l15;
        bf16x8 bfr = *(const bf16x8*)(lds + 4096 + row * 128 +
                                      ((kk * 64 + g4 * 16) ^ ((row & 7) << 4)));
        acc[n] = __builtin_amdgcn_mfma_f32_16x16x32_bf16(af, bfr, acc[n], 0, 0, 0);
      }
      if (wn == 0)
        accg = __builtin_amdgcn_mfma_f32_16x16x32_bf16(af, gf, accg, 0, 0, 0);
    }
  }

  // gate softmax: wn==0 waves
  if (wn == 0) {
    float gbv = gb[l15 & 3];
#pragma unroll
    for (int jj = 0; jj < 4; ++jj) {
      float v = accg[jj] + gbv;
      float mx = fmaxf(v, __shfl_xor(v, 1));
      mx = fmaxf(mx, __shfl_xor(mx, 2));
      float ev = __expf(v - mx);
      float sm = ev + __shfl_xor(ev, 1);
      sm += __shfl_xor(sm, 2);
      if (l15 < 4) gls[(wm * 16 + g4 * 4 + jj) * 4 + l15] = ev / sm;
    }
  }
  __syncthreads();

  // bounce: relu*gate -> bf16 into Bs region
  int e = ybl * 2 + wn;
#pragma unroll
  for (int n = 0; n < 4; ++n) {
#pragma unroll
    for (int jj = 0; jj < 4; ++jj) {
      int row = wm * 16 + g4 * 4 + jj;
      int col = wn * 64 + n * 16 + l15;
      float v = fmaxf(acc[n][jj], 0.f) * gls[row * 4 + e];
      *(unsigned short*)(lds + 4096 + row * 256 + ((col * 2) ^ ((row & 7) << 4))) = f2bf(v);
    }
  }
  __syncthreads();

#pragma unroll
  for (int i = 0; i < 2; ++i) {
    int row = i * 16 + (t >> 4);
    int seg = (t & 15) * 16;
    u16x8 v = *(const u16x8*)(lds + 4096 + row * 256 + (seg ^ ((row & 7) << 4)));
    *(u16x8*)(Hg + (size_t)(m0 + row) * 256 + n0 + (seg >> 1)) = v;
  }
}

// ---------------- GEMM2 + residual epilogue (bounced, fully coalesced) ----------------
// BM=64 BN=128 BK=64. 2048 blocks, XCD-paired remap.
// same_x: layer-0 shortcut — xcur and x0b are the same buffer, load once.
__global__ __launch_bounds__(256) void k2_kernel(const unsigned short* __restrict__ A,
                                                 const unsigned short* __restrict__ Bw,
                                                 const unsigned short* __restrict__ x0b,
                                                 const float* __restrict__ x0f,
                                                 const unsigned short* __restrict__ xcur,
                                                 const float* __restrict__ biasl,
                                                 unsigned short* __restrict__ xnext,
                                                 float* __restrict__ out,
                                                 int last, int use_x0b, int same_x) {
  constexpr int K = 256;
  __shared__ char lds[24576];  // As 8KB | Bs 16KB (Bs reused as acc bounce)
  int t = threadIdx.x;
  int wid = t >> 6, lane = t & 63;
  int g4 = lane >> 4, l15 = lane & 15;
  int wm = wid >> 1, wn = wid & 1;

  // XCD-pair remap: j in [0,2048) -> (xbl in [0,256), ybl in [0,8))
  int j = blockIdx.x;
  int s = j >> 3;
  int xbl = (j & 7) * 32 + (s >> 3);
  int ybl = s & 7;
  int m0 = xbl * 64, n0 = ybl * 128;

  int srow = t >> 3;
  int scolb = ((t & 7) * 16) ^ ((srow & 7) << 4);
  const unsigned short* Asrc = A + (size_t)(m0 + srow) * K + (scolb >> 1);
  const unsigned short* Bsrc = Bw + (size_t)(n0 + srow) * K + (scolb >> 1);

  f32x4 acc[2][4];
#pragma unroll
  for (int m = 0; m < 2; ++m)
#pragma unroll
    for (int n = 0; n < 4; ++n) { f32x4 z = {0.f, 0.f, 0.f, 0.f}; acc[m][n] = z; }

  for (int ks = 0; ks < K; ks += 64) {
    __syncthreads();
#pragma unroll
    for (int i = 0; i < 2; ++i)
      __builtin_amdgcn_global_load_lds(
          (const __attribute__((address_space(1))) void*)(Asrc + (size_t)i * 32 * K + ks),
          (__attribute__((address_space(3))) void*)(lds + i * 4096 + wid * 1024), 16, 0, 0);
#pragma unroll
    for (int i = 0; i < 4; ++i)
      __builtin_amdgcn_global_load_lds(
          (const __attribute__((address_space(1))) void*)(Bsrc + (size_t)i * 32 * K + ks),
          (__attribute__((address_space(3))) void*)(lds + 8192 + i * 4096 + wid * 1024), 16, 0, 0);
    __syncthreads();
#pragma unroll
    for (int kk = 0; kk < 2; ++kk) {
      bf16x8 af[2];
#pragma unroll
      for (int m = 0; m < 2; ++m) {
        int row = wm * 32 + m * 16 + l15;
        af[m] = *(const bf16x8*)(lds + row * 128 + ((kk * 64 + g4 * 16) ^ ((row & 7) << 4)));
      }
#pragma unroll
      for (int n = 0; n < 4; ++n) {
        int row = wn * 64 + n * 16 + l15;
        bf16x8 bfr = *(const bf16x8*)(lds + 8192 + row * 128 +
                                      ((kk * 64 + g4 * 16) ^ ((row & 7) << 4)));
#pragma unroll
        for (int m = 0; m < 2; ++m)
          acc[m][n] = __builtin_amdgcn_mfma_f32_16x16x32_bf16(af[m], bfr, acc[m][n], 0, 0, 0);
      }
    }
  }
  __syncthreads();

  // bounce mixed (acc) as bf16 into Bs region
#pragma unroll
  for (int m = 0; m < 2; ++m) {
#pragma unroll
    for (int n = 0; n < 4; ++n) {
#pragma unroll
      for (int jj = 0; jj < 4; ++jj) {
        int row = wm * 32 + m * 16 + g4 * 4 + jj;
        int col = wn * 64 + n * 16 + l15;
        *(unsigned short*)(lds + 8192 + row * 256 + ((col * 2) ^ ((row & 7) << 4))) =
            f2bf(acc[m][n][jj]);
      }
    }
  }
  __syncthreads();

  // store pass: fully coalesced epilogue math
#pragma unroll
  for (int i = 0; i < 4; ++i) {
    int row = i * 16 + (t >> 4);
    int seg = (t & 15) * 16;
    u16x8 a8 = *(const u16x8*)(lds + 8192 + row * 256 + (seg ^ ((row & 7) << 4)));
    size_t goff = (size_t)(m0 + row) * 1024 + n0 + (seg >> 1);
    u16x8 cv = *(const u16x8*)(xcur + goff);
    float x0v[8];
    if (same_x) {
#pragma unroll
      for (int k = 0; k < 8; ++k) x0v[k] = bf2f(cv[k]);
    } else if (use_x0b) {
      u16x8 xv = *(const u16x8*)(x0b + goff);
#pragma unroll
      for (int k = 0; k < 8; ++k) x0v[k] = bf2f(xv[k]);
    } else {
      f32x4 xa = *(const f32x4*)(x0f + goff);
      f32x4 xb2 = *(const f32x4*)(x0f + goff + 4);
#pragma unroll
      for (int k = 0; k < 4; ++k) { x0v[k] = xa[k]; x0v[k + 4] = xb2[k]; }
    }
    const float* bp = biasl + n0 + (seg >> 1);
    f32x4 b0 = *(const f32x4*)bp;
    f32x4 b1 = *(const f32x4*)(bp + 4);
    float r[8];
#pragma unroll
    for (int k = 0; k < 8; ++k) {
      float bv = (k < 4) ? b0[k & 3] : b1[k & 3];
      r[k] = x0v[k] * bf2f(a8[k]) + bv + bf2f(cv[k]);
    }
    if (last) {
      f32x4 r0, r1;
#pragma unroll
      for (int k = 0; k < 4; ++k) { r0[k] = r[k]; r1[k] = r[k + 4]; }
      *(f32x4*)(out + goff) = r0;
      *(f32x4*)(out + goff + 4) = r1;
    } else {
      u16x8 o;
#pragma unroll
      for (int k = 0; k < 8; ++k) o[k] = f2bf(r[k]);
      *(u16x8*)(xnext + goff) = o;
    }
  }
}

// ---------------- host ----------------
extern "C" void kernel_launch(void* const* d_in, const int* in_sizes, int n_in,
                              void* d_out, int out_size, void* d_ws, size_t ws_size,
                              hipStream_t stream) {
  const float* x0 = (const float*)d_in[0];
  const float* U = (const float*)d_in[1];
  const float* V = (const float*)d_in[2];
  const float* gW = (const float*)d_in[3];
  const float* gb = (const float*)d_in[4];
  const float* bias = (const float*)d_in[5];
  float* out = (float*)d_out;
  char* ws = (char*)d_ws;

  const size_t SZ_X = 33554432;   // 16384*1024*2
  const size_t SZ_HG = 8388608;   // 16384*256*2
  const size_t SZ_W = 1572864;    // 3*256*1024*2
  const size_t SZ_GW = 98304;     // 3*16*1024*2
  bool use_x0b = ws_size >= (2 * SZ_X + SZ_HG + 2 * SZ_W + SZ_GW);

  size_t off = 0;
  unsigned short* x0b = nullptr;
  if (use_x0b) { x0b = (unsigned short*)(ws + off); off += SZ_X; }
  unsigned short* xbf = (unsigned short*)(ws + off); off += SZ_X;
  unsigned short* hg = (unsigned short*)(ws + off); off += SZ_HG;
  unsigned short* W1T = (unsigned short*)(ws + off); off += SZ_W;
  unsigned short* V2T = (unsigned short*)(ws + off); off += SZ_W;
  unsigned short* gWT = (unsigned short*)(ws + off); off += SZ_GW;

  unsigned short* xinit = use_x0b ? x0b : xbf;  // bf16 copy of x0

  cast_x0_kernel<<<8192, 256, 0, stream>>>(x0, xinit);
  pack_w1_kernel<<<3072, 256, 0, stream>>>(U, W1T);
  pack_v2_kernel<<<3072, 256, 0, stream>>>(V, V2T);
  pack_gw_kernel<<<192, 256, 0, stream>>>(gW, gWT);

  for (int l = 0; l < 3; ++l) {
    const unsigned short* xs = (l == 0) ? xinit : xbf;
    int same_x = (l == 0 && use_x0b) ? 1 : 0;  // layer 0: xcur == x0b, load once
    k1_kernel<<<1024, 256, 0, stream>>>(xs, W1T + l * 262144, gWT + l * 16384,
                                        gb + l * 4, hg);
    k2_kernel<<<2048, 256, 0, stream>>>(hg, V2T + l * 262144,
                                        use_x0b ? x0b : nullptr, x0, xs,
                                        bias + l * 1024, xbf, out,
                                        (l == 2) ? 1 : 0, use_x0b ? 1 : 0, same_x);
  }
}

// Round 16
// 175.285 us; speedup vs baseline: 1.2539x; 1.0020x over previous
//
#include <hip/hip_runtime.h>

#define DEVI __device__ __forceinline__

typedef __bf16 bf16x8 __attribute__((ext_vector_type(8)));
typedef float f32x4 __attribute__((ext_vector_type(4)));
typedef unsigned short u16x8 __attribute__((ext_vector_type(8)));

DEVI unsigned short f2bf(float f) {
  unsigned u = __builtin_bit_cast(unsigned, f);
  u += 0x7FFFu + ((u >> 16) & 1u);
  return (unsigned short)(u >> 16);
}
DEVI float bf2f(unsigned short h) {
  return __builtin_bit_cast(float, (unsigned)h << 16);
}

// ---------------- prep kernels ----------------

__global__ __launch_bounds__(256) void cast_x0_kernel(const float* __restrict__ x,
                                                      unsigned short* __restrict__ xb) {
  int i = blockIdx.x * 256 + threadIdx.x;  // i < 2097152
  const f32x4* p = (const f32x4*)x;
  f32x4 a = p[2 * i], b = p[2 * i + 1];
  u16x8 o;
  o[0] = f2bf(a[0]); o[1] = f2bf(a[1]); o[2] = f2bf(a[2]); o[3] = f2bf(a[3]);
  o[4] = f2bf(b[0]); o[5] = f2bf(b[1]); o[6] = f2bf(b[2]); o[7] = f2bf(b[3]);
  ((u16x8*)xb)[i] = o;
}

// U[L,E,D,R] -> W1T[l][n=e*64+r][k=d] bf16
__global__ __launch_bounds__(256) void pack_w1_kernel(const float* __restrict__ U,
                                                      unsigned short* __restrict__ W1T) {
  int idx = blockIdx.x * 256 + threadIdx.x;
  int l = idx >> 18;
  int rem = idx & 262143;
  int n = rem >> 10, k = rem & 1023;
  int e = n >> 6, r = n & 63;
  W1T[idx] = f2bf(U[(size_t)(((l * 4 + e) << 10) + k) * 64 + r]);
}

// V[L,E,R,D] -> V2T[l][d][c=e*64+r] bf16
__global__ __launch_bounds__(256) void pack_v2_kernel(const float* __restrict__ V,
                                                      unsigned short* __restrict__ V2T) {
  int idx = blockIdx.x * 256 + threadIdx.x;
  int l = idx >> 18;
  int rem = idx & 262143;
  int d = rem >> 8, c = rem & 255;
  int e = c >> 6, r = c & 63;
  V2T[idx] = f2bf(V[(size_t)(((l * 4 + e) * 64 + r) << 10) + d]);
}

// gW[L,1024,4] fp32 -> gWT[l][n=0..15][k] bf16 (n>=4 zero-padded)
__global__ __launch_bounds__(256) void pack_gw_kernel(const float* __restrict__ gW,
                                                      unsigned short* __restrict__ gWT) {
  int idx = blockIdx.x * 256 + threadIdx.x;  // < 49152
  int l = idx >> 14;
  int n = (idx >> 10) & 15;
  int k = idx & 1023;
  float v = (n < 4) ? gW[l * 4096 + k * 4 + n] : 0.0f;
  gWT[idx] = f2bf(v);
}

// ---------------- GEMM1 + fused gate: hg = relu(x@W1) * softmax(x@gW+gb) ----------------
// BM=32 BN=128 BK=64, 4 waves 2x2, wave tile 16x64. 1024 blocks, XCD-paired remap.
__global__ __launch_bounds__(256) void k1_kernel(const unsigned short* __restrict__ A,
                                                 const unsigned short* __restrict__ Bw,
                                                 const unsigned short* __restrict__ gWT,
                                                 const float* __restrict__ gb,
                                                 unsigned short* __restrict__ Hg) {
  constexpr int K = 1024;
  __shared__ char lds[20480];  // As 4KB | Bs 16KB (reused: hg bounce 8KB)
  __shared__ float gls[128];   // gate [32][4]
  int t = threadIdx.x;
  int wid = t >> 6, lane = t & 63;
  int g4 = lane >> 4, l15 = lane & 15;
  int wm = wid >> 1, wn = wid & 1;

  // XCD-pair remap: j -> (p in [0,512), ybl in {0,1})
  int j = blockIdx.x;
  int s = j >> 3;
  int p = (j & 7) * 64 + (s >> 1);
  int ybl = s & 1;
  int m0 = p * 32, n0 = ybl * 128;

  int srow = t >> 3;
  int scolb = ((t & 7) * 16) ^ ((srow & 7) << 4);
  const unsigned short* Asrc = A + (size_t)(m0 + srow) * K + (scolb >> 1);
  const unsigned short* Bsrc = Bw + (size_t)(n0 + srow) * K + (scolb >> 1);

  f32x4 acc[4], accg;
  {
    f32x4 z = {0.f, 0.f, 0.f, 0.f};
    accg = z;
#pragma unroll
    for (int n = 0; n < 4; ++n) acc[n] = z;
  }

  for (int ks = 0; ks < K; ks += 64) {
    __syncthreads();
    __builtin_amdgcn_global_load_lds(
        (const __attribute__((address_space(1))) void*)(Asrc + ks),
        (__attribute__((address_space(3))) void*)(lds + wid * 1024), 16, 0, 0);
#pragma unroll
    for (int i = 0; i < 4; ++i)
      __builtin_amdgcn_global_load_lds(
          (const __attribute__((address_space(1))) void*)(Bsrc + (size_t)i * 32 * K + ks),
          (__attribute__((address_space(3))) void*)(lds + 4096 + i * 4096 + wid * 1024), 16, 0, 0);
    __syncthreads();
#pragma unroll
    for (int kk = 0; kk < 2; ++kk) {
      bf16x8 af;
      {
        int row = wm * 16 + l15;
        af = *(const bf16x8*)(lds + row * 128 + ((kk * 64 + g4 * 16) ^ ((row & 7) << 4)));
      }
      bf16x8 gf;
      if (wn == 0) gf = *(const bf16x8*)(gWT + (size_t)l15 * 1024 + ks + kk * 32 + g4 * 8);
#pragma unroll
      for (int n = 0; n < 4; ++n) {
        int row = wn * 64 + n * 16 + l15;
        bf16x8 bfr = *(const bf16x8*)(lds + 4096 + row * 128 +
                                      ((kk * 64 + g4 * 16) ^ ((row & 7) << 4)));
        acc[n] = __builtin_amdgcn_mfma_f32_16x16x32_bf16(af, bfr, acc[n], 0, 0, 0);
      }
      if (wn == 0)
        accg = __builtin_amdgcn_mfma_f32_16x16x32_bf16(af, gf, accg, 0, 0, 0);
    }
  }

  // gate softmax: wn==0 waves
  if (wn == 0) {
    float gbv = gb[l15 & 3];
#pragma unroll
    for (int jj = 0; jj < 4; ++jj) {
      float v = accg[jj] + gbv;
      float mx = fmaxf(v, __shfl_xor(v, 1));
      mx = fmaxf(mx, __shfl_xor(mx, 2));
      float ev = __expf(v - mx);
      float sm = ev + __shfl_xor(ev, 1);
      sm += __shfl_xor(sm, 2);
      if (l15 < 4) gls[(wm * 16 + g4 * 4 + jj) * 4 + l15] = ev / sm;
    }
  }
  __syncthreads();

  // bounce: relu*gate -> bf16 into Bs region
  int e = ybl * 2 + wn;
#pragma unroll
  for (int n = 0; n < 4; ++n) {
#pragma unroll
    for (int jj = 0; jj < 4; ++jj) {
      int row = wm * 16 + g4 * 4 + jj;
      int col = wn * 64 + n * 16 + l15;
      float v = fmaxf(acc[n][jj], 0.f) * gls[row * 4 + e];
      *(unsigned short*)(lds + 4096 + row * 256 + ((col * 2) ^ ((row & 7) << 4))) = f2bf(v);
    }
  }
  __syncthreads();

#pragma unroll
  for (int i = 0; i < 2; ++i) {
    int row = i * 16 + (t >> 4);
    int seg = (t & 15) * 16;
    u16x8 v = *(const u16x8*)(lds + 4096 + row * 256 + (seg ^ ((row & 7) << 4)));
    *(u16x8*)(Hg + (size_t)(m0 + row) * 256 + n0 + (seg >> 1)) = v;
  }
}

// ---------------- GEMM2 + residual epilogue (BM=32 M-split, bounced, coalesced) ----------------
// BM=32 BN=128 BK=64, 4 waves 2x2, wave tile 16x64. LDS 20.5KB -> 7 blocks/CU.
// grid 4096; XCD-16 remap: 16 siblings sharing an hg band -> same XCD, adjacent.
__global__ __launch_bounds__(256) void k2_kernel(const unsigned short* __restrict__ A,
                                                 const unsigned short* __restrict__ Bw,
                                                 const unsigned short* __restrict__ x0b,
                                                 const float* __restrict__ x0f,
                                                 const unsigned short* __restrict__ xcur,
                                                 const float* __restrict__ biasl,
                                                 unsigned short* __restrict__ xnext,
                                                 float* __restrict__ out,
                                                 int last, int use_x0b, int same_x) {
  constexpr int K = 256;
  __shared__ char lds[20480];  // As 4KB [0,4096) | Bs 16KB [4096,20480); bounce reuses Bs
  int t = threadIdx.x;
  int wid = t >> 6, lane = t & 63;
  int g4 = lane >> 4, l15 = lane & 15;
  int wm = wid >> 1, wn = wid & 1;

  // XCD-16 remap: j in [0,4096) -> (xbl in [0,512), ybl in [0,8))
  int j = blockIdx.x;
  int s = j >> 3;
  int xbl = (j & 7) * 64 + (s >> 3);
  int ybl = s & 7;
  int m0 = xbl * 32, n0 = ybl * 128;

  int srow = t >> 3;
  int scolb = ((t & 7) * 16) ^ ((srow & 7) << 4);
  const unsigned short* Asrc = A + (size_t)(m0 + srow) * K + (scolb >> 1);
  const unsigned short* Bsrc = Bw + (size_t)(n0 + srow) * K + (scolb >> 1);

  f32x4 acc[4];
#pragma unroll
  for (int n = 0; n < 4; ++n) { f32x4 z = {0.f, 0.f, 0.f, 0.f}; acc[n] = z; }

  for (int ks = 0; ks < K; ks += 64) {
    __syncthreads();
    __builtin_amdgcn_global_load_lds(
        (const __attribute__((address_space(1))) void*)(Asrc + ks),
        (__attribute__((address_space(3))) void*)(lds + wid * 1024), 16, 0, 0);
#pragma unroll
    for (int i = 0; i < 4; ++i)
      __builtin_amdgcn_global_load_lds(
          (const __attribute__((address_space(1))) void*)(Bsrc + (size_t)i * 32 * K + ks),
          (__attribute__((address_space(3))) void*)(lds + 4096 + i * 4096 + wid * 1024), 16, 0, 0);
    __syncthreads();
#pragma unroll
    for (int kk = 0; kk < 2; ++kk) {
      bf16x8 af;
      {
        int row = wm * 16 + l15;
        af = *(const bf16x8*)(lds + row * 128 + ((kk * 64 + g4 * 16) ^ ((row & 7) << 4)));
      }
#pragma unroll
      for (int n = 0; n < 4; ++n) {
        int row = wn * 64 + n * 16 + l15;
        bf16x8 bfr = *(const bf16x8*)(lds + 4096 + row * 128 +
                                      ((kk * 64 + g4 * 16) ^ ((row & 7) << 4)));
        acc[n] = __builtin_amdgcn_mfma_f32_16x16x32_bf16(af, bfr, acc[n], 0, 0, 0);
      }
    }
  }
  __syncthreads();

  // bounce mixed (acc) as bf16 into Bs region ([32] rows x 256B, swizzled)
#pragma unroll
  for (int n = 0; n < 4; ++n) {
#pragma unroll
    for (int jj = 0; jj < 4; ++jj) {
      int row = wm * 16 + g4 * 4 + jj;
      int col = wn * 64 + n * 16 + l15;
      *(unsigned short*)(lds + 4096 + row * 256 + ((col * 2) ^ ((row & 7) << 4))) =
          f2bf(acc[n][jj]);
    }
  }
  __syncthreads();

  // store pass: fully coalesced epilogue math (2 passes of 16 rows)
#pragma unroll
  for (int i = 0; i < 2; ++i) {
    int row = i * 16 + (t >> 4);
    int seg = (t & 15) * 16;
    u16x8 a8 = *(const u16x8*)(lds + 4096 + row * 256 + (seg ^ ((row & 7) << 4)));
    size_t goff = (size_t)(m0 + row) * 1024 + n0 + (seg >> 1);
    u16x8 cv = *(const u16x8*)(xcur + goff);
    float x0v[8];
    if (same_x) {
#pragma unroll
      for (int k = 0; k < 8; ++k) x0v[k] = bf2f(cv[k]);
    } else if (use_x0b) {
      u16x8 xv = *(const u16x8*)(x0b + goff);
#pragma unroll
      for (int k = 0; k < 8; ++k) x0v[k] = bf2f(xv[k]);
    } else {
      f32x4 xa = *(const f32x4*)(x0f + goff);
      f32x4 xb2 = *(const f32x4*)(x0f + goff + 4);
#pragma unroll
      for (int k = 0; k < 4; ++k) { x0v[k] = xa[k]; x0v[k + 4] = xb2[k]; }
    }
    const float* bp = biasl + n0 + (seg >> 1);
    f32x4 b0 = *(const f32x4*)bp;
    f32x4 b1 = *(const f32x4*)(bp + 4);
    float r[8];
#pragma unroll
    for (int k = 0; k < 8; ++k) {
      float bv = (k < 4) ? b0[k & 3] : b1[k & 3];
      r[k] = x0v[k] * bf2f(a8[k]) + bv + bf2f(cv[k]);
    }
    if (last) {
      f32x4 r0, r1;
#pragma unroll
      for (int k = 0; k < 4; ++k) { r0[k] = r[k]; r1[k] = r[k + 4]; }
      *(f32x4*)(out + goff) = r0;
      *(f32x4*)(out + goff + 4) = r1;
    } else {
      u16x8 o;
#pragma unroll
      for (int k = 0; k < 8; ++k) o[k] = f2bf(r[k]);
      *(u16x8*)(xnext + goff) = o;
    }
  }
}

// ---------------- host ----------------
extern "C" void kernel_launch(void* const* d_in, const int* in_sizes, int n_in,
                              void* d_out, int out_size, void* d_ws, size_t ws_size,
                              hipStream_t stream) {
  const float* x0 = (const float*)d_in[0];
  const float* U = (const float*)d_in[1];
  const float* V = (const float*)d_in[2];
  const float* gW = (const float*)d_in[3];
  const float* gb = (const float*)d_in[4];
  const float* bias = (const float*)d_in[5];
  float* out = (float*)d_out;
  char* ws = (char*)d_ws;

  const size_t SZ_X = 33554432;   // 16384*1024*2
  const size_t SZ_HG = 8388608;   // 16384*256*2
  const size_t SZ_W = 1572864;    // 3*256*1024*2
  const size_t SZ_GW = 98304;     // 3*16*1024*2
  bool use_x0b = ws_size >= (2 * SZ_X + SZ_HG + 2 * SZ_W + SZ_GW);

  size_t off = 0;
  unsigned short* x0b = nullptr;
  if (use_x0b) { x0b = (unsigned short*)(ws + off); off += SZ_X; }
  unsigned short* xbf = (unsigned short*)(ws + off); off += SZ_X;
  unsigned short* hg = (unsigned short*)(ws + off); off += SZ_HG;
  unsigned short* W1T = (unsigned short*)(ws + off); off += SZ_W;
  unsigned short* V2T = (unsigned short*)(ws + off); off += SZ_W;
  unsigned short* gWT = (unsigned short*)(ws + off); off += SZ_GW;

  unsigned short* xinit = use_x0b ? x0b : xbf;  // bf16 copy of x0

  cast_x0_kernel<<<8192, 256, 0, stream>>>(x0, xinit);
  pack_w1_kernel<<<3072, 256, 0, stream>>>(U, W1T);
  pack_v2_kernel<<<3072, 256, 0, stream>>>(V, V2T);
  pack_gw_kernel<<<192, 256, 0, stream>>>(gW, gWT);

  for (int l = 0; l < 3; ++l) {
    const unsigned short* xs = (l == 0) ? xinit : xbf;
    int same_x = (l == 0 && use_x0b) ? 1 : 0;  // layer 0: xcur == x0b, load once
    k1_kernel<<<1024, 256, 0, stream>>>(xs, W1T + l * 262144, gWT + l * 16384,
                                        gb + l * 4, hg);
    k2_kernel<<<4096, 256, 0, stream>>>(hg, V2T + l * 262144,
                                        use_x0b ? x0b : nullptr, x0, xs,
                                        bias + l * 1024, xbf, out,
                                        (l == 2) ? 1 : 0, use_x0b ? 1 : 0, same_x);
  }
}

// Round 17
// 168.709 us; speedup vs baseline: 1.3027x; 1.0390x over previous
//
#include <hip/hip_runtime.h>

#define DEVI __device__ __forceinline__

typedef __bf16 bf16x8 __attribute__((ext_vector_type(8)));
typedef float f32x4 __attribute__((ext_vector_type(4)));
typedef unsigned short u16x8 __attribute__((ext_vector_type(8)));

DEVI unsigned short f2bf(float f) {
  unsigned u = __builtin_bit_cast(unsigned, f);
  u += 0x7FFFu + ((u >> 16) & 1u);
  return (unsigned short)(u >> 16);
}
DEVI float bf2f(unsigned short h) {
  return __builtin_bit_cast(float, (unsigned)h << 16);
}

// ---------------- fused prep kernel: cast + 3 packs, range-dispatched ----------------
// blocks [0,8192): cast x0 -> bf16 (xinit)
// blocks [8192,11264): pack W1T ; [11264,14336): pack V2T ; [14336,14528): pack gWT
__global__ __launch_bounds__(256) void prep_kernel(const float* __restrict__ x,
                                                   const float* __restrict__ U,
                                                   const float* __restrict__ V,
                                                   const float* __restrict__ gW,
                                                   unsigned short* __restrict__ xb,
                                                   unsigned short* __restrict__ W1T,
                                                   unsigned short* __restrict__ V2T,
                                                   unsigned short* __restrict__ gWT) {
  int b = blockIdx.x;
  if (b < 8192) {
    int i = b * 256 + threadIdx.x;  // i < 2097152
    const f32x4* p = (const f32x4*)x;
    f32x4 a = p[2 * i], b2 = p[2 * i + 1];
    u16x8 o;
    o[0] = f2bf(a[0]); o[1] = f2bf(a[1]); o[2] = f2bf(a[2]); o[3] = f2bf(a[3]);
    o[4] = f2bf(b2[0]); o[5] = f2bf(b2[1]); o[6] = f2bf(b2[2]); o[7] = f2bf(b2[3]);
    ((u16x8*)xb)[i] = o;
  } else if (b < 11264) {
    int idx = (b - 8192) * 256 + threadIdx.x;
    int l = idx >> 18;
    int rem = idx & 262143;
    int n = rem >> 10, k = rem & 1023;
    int e = n >> 6, r = n & 63;
    W1T[idx] = f2bf(U[(size_t)(((l * 4 + e) << 10) + k) * 64 + r]);
  } else if (b < 14336) {
    int idx = (b - 11264) * 256 + threadIdx.x;
    int l = idx >> 18;
    int rem = idx & 262143;
    int d = rem >> 8, c = rem & 255;
    int e = c >> 6, r = c & 63;
    V2T[idx] = f2bf(V[(size_t)(((l * 4 + e) * 64 + r) << 10) + d]);
  } else {
    int idx = (b - 14336) * 256 + threadIdx.x;  // < 49152
    int l = idx >> 14;
    int n = (idx >> 10) & 15;
    int k = idx & 1023;
    float v = (n < 4) ? gW[l * 4096 + k * 4 + n] : 0.0f;
    gWT[idx] = f2bf(v);
  }
}

// ---------------- GEMM1 + fused gate: hg = relu(x@W1) * softmax(x@gW+gb) ----------------
// BM=32 BN=128 BK=64, 4 waves 2x2, wave tile 16x64. 1024 blocks, XCD-paired remap.
__global__ __launch_bounds__(256) void k1_kernel(const unsigned short* __restrict__ A,
                                                 const unsigned short* __restrict__ Bw,
                                                 const unsigned short* __restrict__ gWT,
                                                 const float* __restrict__ gb,
                                                 unsigned short* __restrict__ Hg) {
  constexpr int K = 1024;
  __shared__ char lds[20480];  // As 4KB | Bs 16KB (reused: hg bounce 8KB)
  __shared__ float gls[128];   // gate [32][4]
  int t = threadIdx.x;
  int wid = t >> 6, lane = t & 63;
  int g4 = lane >> 4, l15 = lane & 15;
  int wm = wid >> 1, wn = wid & 1;

  // XCD-pair remap: j -> (p in [0,512), ybl in {0,1})
  int j = blockIdx.x;
  int s = j >> 3;
  int p = (j & 7) * 64 + (s >> 1);
  int ybl = s & 1;
  int m0 = p * 32, n0 = ybl * 128;

  int srow = t >> 3;
  int scolb = ((t & 7) * 16) ^ ((srow & 7) << 4);
  const unsigned short* Asrc = A + (size_t)(m0 + srow) * K + (scolb >> 1);
  const unsigned short* Bsrc = Bw + (size_t)(n0 + srow) * K + (scolb >> 1);

  f32x4 acc[4], accg;
  {
    f32x4 z = {0.f, 0.f, 0.f, 0.f};
    accg = z;
#pragma unroll
    for (int n = 0; n < 4; ++n) acc[n] = z;
  }

  for (int ks = 0; ks < K; ks += 64) {
    __syncthreads();
    __builtin_amdgcn_global_load_lds(
        (const __attribute__((address_space(1))) void*)(Asrc + ks),
        (__attribute__((address_space(3))) void*)(lds + wid * 1024), 16, 0, 0);
#pragma unroll
    for (int i = 0; i < 4; ++i)
      __builtin_amdgcn_global_load_lds(
          (const __attribute__((address_space(1))) void*)(Bsrc + (size_t)i * 32 * K + ks),
          (__attribute__((address_space(3))) void*)(lds + 4096 + i * 4096 + wid * 1024), 16, 0, 0);
    __syncthreads();
#pragma unroll
    for (int kk = 0; kk < 2; ++kk) {
      bf16x8 af;
      {
        int row = wm * 16 + l15;
        af = *(const bf16x8*)(lds + row * 128 + ((kk * 64 + g4 * 16) ^ ((row & 7) << 4)));
      }
      bf16x8 gf;
      if (wn == 0) gf = *(const bf16x8*)(gWT + (size_t)l15 * 1024 + ks + kk * 32 + g4 * 8);
#pragma unroll
      for (int n = 0; n < 4; ++n) {
        int row = wn * 64 + n * 16 + l15;
        bf16x8 bfr = *(const bf16x8*)(lds + 4096 + row * 128 +
                                      ((kk * 64 + g4 * 16) ^ ((row & 7) << 4)));
        acc[n] = __builtin_amdgcn_mfma_f32_16x16x32_bf16(af, bfr, acc[n], 0, 0, 0);
      }
      if (wn == 0)
        accg = __builtin_amdgcn_mfma_f32_16x16x32_bf16(af, gf, accg, 0, 0, 0);
    }
  }

  // gate softmax: wn==0 waves
  if (wn == 0) {
    float gbv = gb[l15 & 3];
#pragma unroll
    for (int jj = 0; jj < 4; ++jj) {
      float v = accg[jj] + gbv;
      float mx = fmaxf(v, __shfl_xor(v, 1));
      mx = fmaxf(mx, __shfl_xor(mx, 2));
      float ev = __expf(v - mx);
      float sm = ev + __shfl_xor(ev, 1);
      sm += __shfl_xor(sm, 2);
      if (l15 < 4) gls[(wm * 16 + g4 * 4 + jj) * 4 + l15] = ev / sm;
    }
  }
  __syncthreads();

  // bounce: relu*gate -> bf16 into Bs region
  int e = ybl * 2 + wn;
#pragma unroll
  for (int n = 0; n < 4; ++n) {
#pragma unroll
    for (int jj = 0; jj < 4; ++jj) {
      int row = wm * 16 + g4 * 4 + jj;
      int col = wn * 64 + n * 16 + l15;
      float v = fmaxf(acc[n][jj], 0.f) * gls[row * 4 + e];
      *(unsigned short*)(lds + 4096 + row * 256 + ((col * 2) ^ ((row & 7) << 4))) = f2bf(v);
    }
  }
  __syncthreads();

#pragma unroll
  for (int i = 0; i < 2; ++i) {
    int row = i * 16 + (t >> 4);
    int seg = (t & 15) * 16;
    u16x8 v = *(const u16x8*)(lds + 4096 + row * 256 + (seg ^ ((row & 7) << 4)));
    *(u16x8*)(Hg + (size_t)(m0 + row) * 256 + n0 + (seg >> 1)) = v;
  }
}

// ---------------- GEMM2 + residual epilogue (BM=32 M-split, bounced, coalesced) ----------------
// BM=32 BN=128 BK=64, 4 waves 2x2, wave tile 16x64. grid 4096; XCD-16 remap.
__global__ __launch_bounds__(256) void k2_kernel(const unsigned short* __restrict__ A,
                                                 const unsigned short* __restrict__ Bw,
                                                 const unsigned short* __restrict__ x0b,
                                                 const float* __restrict__ x0f,
                                                 const unsigned short* __restrict__ xcur,
                                                 const float* __restrict__ biasl,
                                                 unsigned short* __restrict__ xnext,
                                                 float* __restrict__ out,
                                                 int last, int use_x0b, int same_x) {
  constexpr int K = 256;
  __shared__ char lds[20480];  // As 4KB [0,4096) | Bs 16KB [4096,20480); bounce reuses Bs
  int t = threadIdx.x;
  int wid = t >> 6, lane = t & 63;
  int g4 = lane >> 4, l15 = lane & 15;
  int wm = wid >> 1, wn = wid & 1;

  // XCD-16 remap: j in [0,4096) -> (xbl in [0,512), ybl in [0,8))
  int j = blockIdx.x;
  int s = j >> 3;
  int xbl = (j & 7) * 64 + (s >> 3);
  int ybl = s & 7;
  int m0 = xbl * 32, n0 = ybl * 128;

  int srow = t >> 3;
  int scolb = ((t & 7) * 16) ^ ((srow & 7) << 4);
  const unsigned short* Asrc = A + (size_t)(m0 + srow) * K + (scolb >> 1);
  const unsigned short* Bsrc = Bw + (size_t)(n0 + srow) * K + (scolb >> 1);

  f32x4 acc[4];
#pragma unroll
  for (int n = 0; n < 4; ++n) { f32x4 z = {0.f, 0.f, 0.f, 0.f}; acc[n] = z; }

  for (int ks = 0; ks < K; ks += 64) {
    __syncthreads();
    __builtin_amdgcn_global_load_lds(
        (const __attribute__((address_space(1))) void*)(Asrc + ks),
        (__attribute__((address_space(3))) void*)(lds + wid * 1024), 16, 0, 0);
#pragma unroll
    for (int i = 0; i < 4; ++i)
      __builtin_amdgcn_global_load_lds(
          (const __attribute__((address_space(1))) void*)(Bsrc + (size_t)i * 32 * K + ks),
          (__attribute__((address_space(3))) void*)(lds + 4096 + i * 4096 + wid * 1024), 16, 0, 0);
    __syncthreads();
#pragma unroll
    for (int kk = 0; kk < 2; ++kk) {
      bf16x8 af;
      {
        int row = wm * 16 + l15;
        af = *(const bf16x8*)(lds + row * 128 + ((kk * 64 + g4 * 16) ^ ((row & 7) << 4)));
      }
#pragma unroll
      for (int n = 0; n < 4; ++n) {
        int row = wn * 64 + n * 16 + l15;
        bf16x8 bfr = *(const bf16x8*)(lds + 4096 + row * 128 +
                                      ((kk * 64 + g4 * 16) ^ ((row & 7) << 4)));
        acc[n] = __builtin_amdgcn_mfma_f32_16x16x32_bf16(af, bfr, acc[n], 0, 0, 0);
      }
    }
  }
  __syncthreads();

  // bounce mixed (acc) as bf16 into Bs region ([32] rows x 256B, swizzled)
#pragma unroll
  for (int n = 0; n < 4; ++n) {
#pragma unroll
    for (int jj = 0; jj < 4; ++jj) {
      int row = wm * 16 + g4 * 4 + jj;
      int col = wn * 64 + n * 16 + l15;
      *(unsigned short*)(lds + 4096 + row * 256 + ((col * 2) ^ ((row & 7) << 4))) =
          f2bf(acc[n][jj]);
    }
  }
  __syncthreads();

  // store pass: fully coalesced epilogue math (2 passes of 16 rows)
#pragma unroll
  for (int i = 0; i < 2; ++i) {
    int row = i * 16 + (t >> 4);
    int seg = (t & 15) * 16;
    u16x8 a8 = *(const u16x8*)(lds + 4096 + row * 256 + (seg ^ ((row & 7) << 4)));
    size_t goff = (size_t)(m0 + row) * 1024 + n0 + (seg >> 1);
    u16x8 cv = *(const u16x8*)(xcur + goff);
    float x0v[8];
    if (same_x) {
#pragma unroll
      for (int k = 0; k < 8; ++k) x0v[k] = bf2f(cv[k]);
    } else if (use_x0b) {
      u16x8 xv = *(const u16x8*)(x0b + goff);
#pragma unroll
      for (int k = 0; k < 8; ++k) x0v[k] = bf2f(xv[k]);
    } else {
      f32x4 xa = *(const f32x4*)(x0f + goff);
      f32x4 xb2 = *(const f32x4*)(x0f + goff + 4);
#pragma unroll
      for (int k = 0; k < 4; ++k) { x0v[k] = xa[k]; x0v[k + 4] = xb2[k]; }
    }
    const float* bp = biasl + n0 + (seg >> 1);
    f32x4 b0 = *(const f32x4*)bp;
    f32x4 b1 = *(const f32x4*)(bp + 4);
    float r[8];
#pragma unroll
    for (int k = 0; k < 8; ++k) {
      float bv = (k < 4) ? b0[k & 3] : b1[k & 3];
      r[k] = x0v[k] * bf2f(a8[k]) + bv + bf2f(cv[k]);
    }
    if (last) {
      f32x4 r0, r1;
#pragma unroll
      for (int k = 0; k < 4; ++k) { r0[k] = r[k]; r1[k] = r[k + 4]; }
      *(f32x4*)(out + goff) = r0;
      *(f32x4*)(out + goff + 4) = r1;
    } else {
      u16x8 o;
#pragma unroll
      for (int k = 0; k < 8; ++k) o[k] = f2bf(r[k]);
      *(u16x8*)(xnext + goff) = o;
    }
  }
}

// ---------------- host ----------------
extern "C" void kernel_launch(void* const* d_in, const int* in_sizes, int n_in,
                              void* d_out, int out_size, void* d_ws, size_t ws_size,
                              hipStream_t stream) {
  const float* x0 = (const float*)d_in[0];
  const float* U = (const float*)d_in[1];
  const float* V = (const float*)d_in[2];
  const float* gW = (const float*)d_in[3];
  const float* gb = (const float*)d_in[4];
  const float* bias = (const float*)d_in[5];
  float* out = (float*)d_out;
  char* ws = (char*)d_ws;

  const size_t SZ_X = 33554432;   // 16384*1024*2
  const size_t SZ_HG = 8388608;   // 16384*256*2
  const size_t SZ_W = 1572864;    // 3*256*1024*2
  const size_t SZ_GW = 98304;     // 3*16*1024*2
  bool use_x0b = ws_size >= (2 * SZ_X + SZ_HG + 2 * SZ_W + SZ_GW);

  size_t off = 0;
  unsigned short* x0b = nullptr;
  if (use_x0b) { x0b = (unsigned short*)(ws + off); off += SZ_X; }
  unsigned short* xbf = (unsigned short*)(ws + off); off += SZ_X;
  unsigned short* hg = (unsigned short*)(ws + off); off += SZ_HG;
  unsigned short* W1T = (unsigned short*)(ws + off); off += SZ_W;
  unsigned short* V2T = (unsigned short*)(ws + off); off += SZ_W;
  unsigned short* gWT = (unsigned short*)(ws + off); off += SZ_GW;

  unsigned short* xinit = use_x0b ? x0b : xbf;  // bf16 copy of x0

  prep_kernel<<<14528, 256, 0, stream>>>(x0, U, V, gW, xinit, W1T, V2T, gWT);

  for (int l = 0; l < 3; ++l) {
    const unsigned short* xs = (l == 0) ? xinit : xbf;
    int same_x = (l == 0 && use_x0b) ? 1 : 0;  // layer 0: xcur == x0b, load once
    k1_kernel<<<1024, 256, 0, stream>>>(xs, W1T + l * 262144, gWT + l * 16384,
                                        gb + l * 4, hg);
    k2_kernel<<<4096, 256, 0, stream>>>(hg, V2T + l * 262144,
                                        use_x0b ? x0b : nullptr, x0, xs,
                                        bias + l * 1024, xbf, out,
                                        (l == 2) ? 1 : 0, use_x0b ? 1 : 0, same_x);
  }
}